// Round 8
// baseline (375.022 us; speedup 1.0000x reference)
//
#include <hip/hip_runtime.h>
#include <stdint.h>

#pragma clang fp contract(off)

#define BB 16
#define NN 25200
#define CCH 85
#define KTOP 512
#define NBKT 1024
#define CAP 1024

// ws layout:
//   conf float[BB*NN] @ 0 (1,612,800)
//   clsw uint8[BB*NN] @ 1,612,800 (403,200)
//   hist uint[BB*1024] @ 2,016,000 (65,536)
//   meta @ 2,097,152; per-batch stride 16,384:
//     bb4 @ +0 (8192) | score @ +8192 (2048) | cls @ +10240 (2048)
#define CLSW0 1612800
#define HIST0 2016000
#define META0 2097152
#define SB 16384

// conf-max + class argmax + global hist (R5 k_conf + R1's proven hist atomic)
__global__ __launch_bounds__(512) void k_conf(const float* __restrict__ x,
                                              float* __restrict__ conf,
                                              uint8_t* __restrict__ clsout,
                                              unsigned* __restrict__ hist) {
    __shared__ float tile[128 * CCH];
    const int blk = blockIdx.x;
    const int tid = threadIdx.x;

    const float4* src = (const float4*)x + (size_t)blk * 2720;
    float4* dst = (float4*)tile;
    for (int i = tid; i < 2720; i += 512) dst[i] = src[i];
    __syncthreads();

    const int r = tid >> 2;          // local row 0..127
    const int q = tid & 3;           // class quarter
    const float* row = tile + r * CCH;
    const float obj = row[4];

    float best = -1.0f;
    int bi = 0;
    const float* cp = row + 5 + q * 20;
#pragma unroll
    for (int j = 0; j < 20; ++j) {
        float p = cp[j] * obj;       // rounded product, same as reference
        if (p > best) { best = p; bi = j; }
    }
    bi += q * 20;

    // position-aware symmetric combine: (max, lowest index on ties)
    float ov = __shfl_xor(best, 1);
    int oi = __shfl_xor(bi, 1);
    if (ov > best || (ov == best && oi < bi)) { best = ov; bi = oi; }
    ov = __shfl_xor(best, 2);
    oi = __shfl_xor(bi, 2);
    if (ov > best || (ov == best && oi < bi)) { best = ov; bi = oi; }

    if (q == 0) {
        const int gr = blk * 128 + r;
        const bool valid = (obj > 0.01f) && (best > 0.01f);
        conf[gr] = valid ? best : -1.0f;
        clsout[gr] = (uint8_t)bi;
        if (valid) {
            const int b = gr / NN;
            int bk = (int)(best * 1024.0f);
            if (bk > NBKT - 1) bk = NBKT - 1;
            atomicAdd(&hist[b * NBKT + bk], 1u);
        }
    }
}

__global__ __launch_bounds__(1024) void k_sel(const float* __restrict__ x,
                                              const uint8_t* __restrict__ clsw,
                                              const float* __restrict__ conf,
                                              const unsigned* __restrict__ hist,
                                              char* __restrict__ meta) {
    __shared__ unsigned long long cand[CAP];
    __shared__ unsigned wsum[16];
    __shared__ int sh_tstar, sh_cnt;

    const int b = blockIdx.x;
    const int tid = threadIdx.x;
    const int lane = tid & 63;
    const float4* cb4 = (const float4*)(conf + (size_t)b * NN);

    // ---- A: wave-hierarchical suffix scan of global hist (3 barriers) ----
    unsigned v = hist[b * NBKT + tid];
    if (tid == 0) { sh_tstar = 0; sh_cnt = 0; }
    unsigned s = v;
#pragma unroll
    for (int d = 1; d < 64; d <<= 1) {
        unsigned t = __shfl_down(s, d);
        if (lane + d < 64) s += t;
    }
    if (lane == 0) wsum[tid >> 6] = s;
    __syncthreads();
    unsigned off = 0;
    for (int w = (tid >> 6) + 1; w < 16; ++w) off += wsum[w];
    unsigned S = s + off;
    if (S >= KTOP && (S - v) < KTOP) sh_tstar = tid;
    __syncthreads();
    const int tstar = sh_tstar;

    // ---- B: single gather pass (uniform trip count; guarded loads) ----
    for (int k = 0; k < 7; ++k) {
        const int i4 = tid + k * 1024;
        float4 c4 = make_float4(-1.f, -1.f, -1.f, -1.f);
        if (i4 < NN / 4) c4 = cb4[i4];
        float cs[4] = {c4.x, c4.y, c4.z, c4.w};
#pragma unroll
        for (int e = 0; e < 4; ++e) {
            float c = cs[e];
            bool want = false;
            if (c > 0.0f) {
                int bk = (int)(c * 1024.0f);
                if (bk > NBKT - 1) bk = NBKT - 1;
                want = (bk >= tstar);
            }
            unsigned long long bal = __ballot(want);
            int base = 0;
            if (lane == 0 && bal) base = atomicAdd(&sh_cnt, __popcll(bal));
            base = __shfl(base, 0);
            if (want) {
                int pos = base + __popcll(bal & ((1ull << lane) - 1ull));
                if (pos < CAP) {
                    unsigned bits = __float_as_uint(c);
                    cand[pos] = ((unsigned long long)bits << 32) | (unsigned)(~(i4 * 4 + e));
                }
            }
        }
    }
    __syncthreads();
    const int M = min(sh_cnt, CAP);

    // ---- C: hybrid bitonic sort, descending; 1 key/thread in register ----
    unsigned long long key = (tid < M) ? cand[tid] : 0ull;
    __syncthreads();
    for (int kk = 2; kk <= CAP; kk <<= 1) {
        for (int j = kk >> 1; j > 0; j >>= 1) {
            unsigned long long partner;
            if (j >= 64) {
                cand[tid] = key;
                __syncthreads();
                partner = cand[tid ^ j];
                __syncthreads();
            } else {
                partner = __shfl_xor(key, j);
            }
            bool desc = (tid & kk) == 0;
            bool lower = (tid & j) == 0;
            bool take_max = (lower == desc);
            bool pg = partner > key;
            key = (take_max == pg) ? partner : key;
        }
    }

    // ---- D (light): top-512 -> boxes/score/cls to meta ----
    char* mb = meta + (size_t)b * SB;
    if (tid < KTOP) {
        float sc = __uint_as_float((unsigned)(key >> 32));
        unsigned idx = ~((unsigned)key);
        bool v2 = sc > 0.0f;
        float X1 = 0.f, Y1 = 0.f, X2 = 0.f, Y2 = 0.f;
        int cl = 0;
        if (v2) {
            const float* rw = x + ((size_t)b * NN + idx) * CCH;
            float cx = rw[0], cy = rw[1];
            float w = rw[2] * 0.5f, h = rw[3] * 0.5f;
            X1 = cx - w; Y1 = cy - h; X2 = cx + w; Y2 = cy + h;
            cl = clsw[(size_t)b * NN + idx];
        }
        ((float4*)mb)[tid] = make_float4(X1, Y1, X2, Y2);
        ((float*)(mb + 8192))[tid] = sc;
        ((int*)(mb + 10240))[tid] = cl;
    }
}

__global__ __launch_bounds__(1024) void k_nms(const float* __restrict__ target,
                                              const char* __restrict__ meta,
                                              float* __restrict__ out) {
    __shared__ unsigned smask[KTOP][16];     // 32 KB
    __shared__ float4 sbb[KTOP];             // 8 KB plain boxes
    __shared__ float4 sox[KTOP];             // 8 KB offset boxes
    __shared__ float sarea[KTOP];            // 2 KB
    __shared__ float sscore[KTOP];           // 2 KB
    __shared__ int scls[KTOP];               // 2 KB
    __shared__ unsigned keep_words[16];
    __shared__ unsigned long long wred[16];

    const int b = blockIdx.x;
    const int tid = threadIdx.x;
    const char* mb = meta + (size_t)b * SB;

    // stage + derive offset boxes/areas (no cross-thread dep before barrier)
    if (tid < KTOP) {
        float4 bx = ((const float4*)mb)[tid];
        float sc = ((const float*)(mb + 8192))[tid];
        int cl = ((const int*)(mb + 10240))[tid];
        sbb[tid] = bx;
        sscore[tid] = sc;
        scls[tid] = cl;
        float offv = (float)cl * 4096.0f;                       // same op as before
        float4 o = make_float4(bx.x + offv, bx.y + offv, bx.z + offv, bx.w + offv);
        sox[tid] = o;
        sarea[tid] = (o.z - o.x) * (o.w - o.y);
    }
    __syncthreads();

    // ---- E: suppression mask in LDS (lower triangle; rotated for banks) ----
    for (int p = tid; p < KTOP * 16; p += 1024) {
        const int i = p >> 4;          // 16 consecutive lanes share i (broadcast)
        const int w = p & 15;
        unsigned bits = 0u;
        if ((w << 5) < i) {
            float4 bi4 = sox[i];
            float ai = sarea[i];
            const int jbase = w << 5;
            for (int t = 0; t < 32; ++t) {
                int jj = (t + w) & 31;     // rotation spreads banks
                int j = jbase + jj;
                float4 bj = sox[j];
                float lx = fmaxf(bi4.x, bj.x);
                float ly = fmaxf(bi4.y, bj.y);
                float rx = fminf(bi4.z, bj.z);
                float ry = fminf(bi4.w, bj.w);
                float inter = fmaxf(rx - lx, 0.0f) * fmaxf(ry - ly, 0.0f);
                float den = ai + sarea[j] - inter + 1e-9f;
                float iou = inter / den;
                unsigned hit = (unsigned)((j < i) & (iou > 0.5f));
                bits |= hit << jj;
            }
        }
        smask[i][w] = bits;
    }
    __syncthreads();

    // ---- F: greedy scan on wave 0, 2-deep prefetch ----
    if (tid < 64) {
        const int l15 = tid & 15;
        unsigned keepw = 0u;
        unsigned r0 = smask[0][l15], r1 = smask[1][l15];
        float s0 = sscore[0], s1 = sscore[1];
        for (int i = 0; i < KTOP; ++i) {
            unsigned r2 = 0u; float s2 = 0.f;
            if (i < KTOP - 2) { r2 = smask[i + 2][l15]; s2 = sscore[i + 2]; }
            unsigned long long bal = __ballot((r0 & keepw) != 0u);
            bool sup = (bal & 0xFFFFull) != 0ull;
            bool kept = (s0 > 0.0f) && !sup;
            if (kept && tid == (i >> 5)) keepw |= (1u << (i & 31));
            r0 = r1; r1 = r2; s0 = s1; s1 = s2;
        }
        if (tid < 16) keep_words[tid] = keepw;
    }
    __syncthreads();

    // ---- G: masked argmax of IoU-with-target, output ----
    const float tb0 = target[0], tb1 = target[1], tb2 = target[2], tb3 = target[3];
    const int tcls = (int)target[5];
    float m = -1.0f;
    if (tid < KTOP) {
        bool kept = (keep_words[tid >> 5] >> (tid & 31)) & 1u;
        if (kept && scls[tid] == tcls) {
            float4 bx = sbb[tid];
            float lx = fmaxf(bx.x, tb0);
            float ly = fmaxf(bx.y, tb1);
            float rx = fminf(bx.z, tb2);
            float ry = fminf(bx.w, tb3);
            float inter = fmaxf(rx - lx, 0.0f) * fmaxf(ry - ly, 0.0f);
            float areab = (bx.z - bx.x) * (bx.w - bx.y);
            float areat = (tb2 - tb0) * (tb3 - tb1);
            float den = areab + areat - inter + 1e-9f;
            m = inter / den;
        }
    }
    unsigned mbb = __float_as_uint(m);
    unsigned mono = (mbb & 0x80000000u) ? ~mbb : (mbb | 0x80000000u);
    unsigned long long rk = ((unsigned long long)mono << 32) | (unsigned)(~tid);
    for (int d = 32; d > 0; d >>= 1) {
        unsigned long long o = __shfl_xor(rk, d);
        if (o > rk) rk = o;
    }
    if ((tid & 63) == 0) wred[tid >> 6] = rk;
    __syncthreads();
    if (tid == 0) {
        unsigned long long bestk = wred[0];
        for (int i = 1; i < 16; ++i)
            if (wred[i] > bestk) bestk = wred[i];
        unsigned mono2 = (unsigned)(bestk >> 32);
        unsigned mbits = (mono2 & 0x80000000u) ? (mono2 & 0x7FFFFFFFu) : ~mono2;
        float mstar = __uint_as_float(mbits);
        int j = (int)(~((unsigned)bestk));
        out[b] = (mstar >= 0.0f) ? sscore[j] * mstar : 0.0f;
    }
}

extern "C" void kernel_launch(void* const* d_in, const int* in_sizes, int n_in,
                              void* d_out, int out_size, void* d_ws, size_t ws_size,
                              hipStream_t stream) {
    const float* x = (const float*)d_in[0];
    const float* target = (const float*)d_in[1];
    float* out = (float*)d_out;

    char* ws = (char*)d_ws;
    float* conf = (float*)ws;
    uint8_t* clsw = (uint8_t*)(ws + CLSW0);
    unsigned* hist = (unsigned*)(ws + HIST0);
    char* meta = ws + META0;

    hipMemsetAsync(hist, 0, BB * NBKT * sizeof(unsigned), stream);
    k_conf<<<dim3((BB * NN) / 128), dim3(512), 0, stream>>>(x, conf, clsw, hist);
    k_sel<<<dim3(BB), dim3(1024), 0, stream>>>(x, clsw, conf, hist, meta);
    k_nms<<<dim3(BB), dim3(1024), 0, stream>>>(target, meta, out);
}